// Round 22
// baseline (144.493 us; speedup 1.0000x reference)
//
#include <hip/hip_runtime.h>
#include <hip/hip_fp8.h>
#include <math.h>

#define L      2048
#define DDIM   512
#define NBATCH 8
#define NTILE  16                        // 128-row tiles
#define NPAIR  (NTILE * (NTILE + 1) / 2) // 136
#define SCREEN_BLOCKS (NBATCH * NPAIR)   // 1088

#define ALPHA  0.1
#define BETA   0.3
#define PAN2   2048      // bytes per packed 32-row x 64-dim fp8 panel

typedef __attribute__((ext_vector_type(16))) float f32x16;
typedef long long2v __attribute__((ext_vector_type(2)));

// ---------------------------------------------------------------------------
// K1: per-(batch, 32-dim chunk, row-half) group sums.
// S_g[d] = sum of x[row][d] over rows with seg==g ; T_g = sum of x^2.
// grid 256 = 8 n x 16 chunks x 2 halves; 256 thr = 8 row-parts x 32 dims.
// No races: LDS slot [p][g][d] owned by exactly one thread (p,d).
// ---------------------------------------------------------------------------
__global__ __launch_bounds__(256) void gsum_kernel(const float* __restrict__ pred,
                                                   const int*   __restrict__ seg,
                                                   float* __restrict__ Spart,
                                                   float* __restrict__ Tpart) {
    __shared__ float Sl[8][16][32];
    __shared__ float Tl[8][16][32];
    int bid  = blockIdx.x;
    int n    = bid & 7;
    int c    = (bid >> 3) & 15;
    int half = bid >> 7;
    int t = threadIdx.x;
    int d = t & 31, p = t >> 5;

    for (int i = t; i < 8 * 16 * 32; i += 256) {
        ((float*)Sl)[i] = 0.0f;
        ((float*)Tl)[i] = 0.0f;
    }
    __syncthreads();

    const float* pb   = pred + (size_t)n * L * DDIM + c * 32 + d;
    const int*   segb = seg + n * L + half * 1024;
    #pragma unroll 4
    for (int i = 0; i < 128; ++i) {
        int lr  = i * 8 + p;                       // 0..1023 within half
        int row = half * 1024 + lr;
        float x = pb[(size_t)row * DDIM];
        int g   = segb[lr];
        Sl[p][g][d] += x;
        Tl[p][g][d] += x * x;
    }
    __syncthreads();

    // reduce over p (fixed order -> deterministic)
    for (int i = t; i < 512; i += 256) {
        int g = i >> 5, dd = i & 31;
        float s = 0.0f, tt = 0.0f;
        #pragma unroll
        for (int q = 0; q < 8; ++q) { s += Sl[q][g][dd]; tt += Tl[q][g][dd]; }
        Spart[((size_t)bid * 16 + g) * 32 + dd] = s;
        Sl[0][g][dd] = tt;                         // reuse for T reduction
    }
    __syncthreads();
    if (t < 16) {
        float tt = 0.0f;
        #pragma unroll
        for (int dd = 0; dd < 32; ++dd) tt += Sl[0][t][dd];
        Tpart[bid * 16 + t] = tt;
    }
}

// ---------------------------------------------------------------------------
// K2: first-64-dims fp32 -> fp8 e4m3 packed in MFMA-fragment order
// (R20/R21-verified layout, PAN2=2048) + exact fp32 sq64 / n64.
// grid 512 (one 32-row panel per block); 256 thr = 32 rows x 8 dim-chunks.
// ---------------------------------------------------------------------------
__global__ __launch_bounds__(256) void conv64_kernel(const float* __restrict__ pred,
                                                     unsigned char* __restrict__ h8,
                                                     float* __restrict__ sq64,
                                                     float* __restrict__ n64) {
    int t    = threadIdx.x;
    int rowl = t >> 3;                 // 0..31
    int d8   = t & 7;                  // 8-dim chunk within first 64
    int row  = blockIdx.x * 32 + rowl; // global row 0..16383
    const float* p = pred + (size_t)row * DDIM + d8 * 8;
    float4 v0 = *(const float4*)(p);
    float4 v1 = *(const float4*)(p + 4);
    float vals[8] = {v0.x, v0.y, v0.z, v0.w, v1.x, v1.y, v1.z, v1.w};
    unsigned q[8];
    float s = 0.0f;
    #pragma unroll
    for (int i = 0; i < 8; ++i) {
        float x = vals[i];
        s = fmaf(x, x, s);
        __hip_fp8_e4m3 f8(x);
        q[i] = (unsigned)f8.__x;
    }
    unsigned lo = q[0] | (q[1] << 8) | (q[2] << 16) | (q[3] << 24);
    unsigned hi = q[4] | (q[5] << 8) | (q[6] << 16) | (q[7] << 24);
    int pair  = d8 >> 2;
    int kodd  = (d8 >> 1) & 1;
    int khalf = d8 & 1;
    size_t off = (size_t)blockIdx.x * PAN2 + pair * 1024
               + ((row & 31) + 32 * khalf) * 16 + kodd * 8;
    *(uint2*)(h8 + off) = make_uint2(lo, hi);
    // 8-thread row reduce (threads t..t+7 share a row)
    s += __shfl_down(s, 4);
    s += __shfl_down(s, 2);
    s += __shfl_down(s, 1);
    if (d8 == 0) { sq64[row] = s; n64[row] = sqrtf(s); }
}

// ---------------------------------------------------------------------------
// K3: 64-dim fp8 screen GEMM (register-direct, R21-verified frag mapping).
// Certifies hinge==0 when d2_est >= 4.5 + 0.27*n_j*n_k (rigorous e4m3 bound:
// |d2_est - d2_64| <= 0.25*nj*nk + 0.3; d2_512 >= d2_64). Survivors (none
// for Gaussian data) take exact fp32 fallback; hinge^2 accumulated via
// EXACT int64 fixed-point atomics (order-independent -> deterministic).
// Symmetric grid (tj<=tk); survivor weight 2 for j<k; j==k / same-seg skip.
// ---------------------------------------------------------------------------
__global__ __launch_bounds__(256) void screen_kernel(
        const unsigned char* __restrict__ h8,
        const float* __restrict__ sq64,
        const float* __restrict__ n64,
        const int*   __restrict__ seg,
        const float* __restrict__ pred,
        unsigned long long* __restrict__ hacc) {
    int bid = blockIdx.x;
    int n = bid & 7;
    int p = bid >> 3;
    int tj = 0;
    while (true) {
        int rl2 = NTILE - tj;
        if (p < rl2) break;
        p -= rl2;
        ++tj;
    }
    int tk = tj + p;

    int t    = threadIdx.x;
    int wid  = t >> 6;
    int lane = t & 63;
    int wr   = wid >> 1, wc = wid & 1;
    int l31  = lane & 31;
    int hsel = lane >> 5;

    // panels are global: panel = global_row >> 5
    const unsigned char* pa0 = h8 + (size_t)(n * 64 + tj * 4 + wr * 2 + 0) * PAN2 + lane * 16;
    const unsigned char* pa1 = pa0 + PAN2;
    const unsigned char* pb0 = h8 + (size_t)(n * 64 + tk * 4 + wc * 2 + 0) * PAN2 + lane * 16;
    const unsigned char* pb1 = pb0 + PAN2;

    f32x16 acc[2][2];
    #pragma unroll
    for (int m = 0; m < 2; ++m)
        #pragma unroll
        for (int nf = 0; nf < 2; ++nf)
            #pragma unroll
            for (int x = 0; x < 16; ++x) acc[m][nf][x] = 0.0f;

    #pragma unroll
    for (int ks2 = 0; ks2 < 2; ++ks2) {        // K = 64 = 2 kspairs
        long2v a0 = *(const long2v*)(pa0 + ks2 * 1024);
        long2v a1 = *(const long2v*)(pa1 + ks2 * 1024);
        long2v b0 = *(const long2v*)(pb0 + ks2 * 1024);
        long2v b1 = *(const long2v*)(pb1 + ks2 * 1024);
        acc[0][0] = __builtin_amdgcn_mfma_f32_32x32x16_fp8_fp8(a0.x, b0.x, acc[0][0], 0, 0, 0);
        acc[0][1] = __builtin_amdgcn_mfma_f32_32x32x16_fp8_fp8(a0.x, b1.x, acc[0][1], 0, 0, 0);
        acc[1][0] = __builtin_amdgcn_mfma_f32_32x32x16_fp8_fp8(a1.x, b0.x, acc[1][0], 0, 0, 0);
        acc[1][1] = __builtin_amdgcn_mfma_f32_32x32x16_fp8_fp8(a1.x, b1.x, acc[1][1], 0, 0, 0);
        acc[0][0] = __builtin_amdgcn_mfma_f32_32x32x16_fp8_fp8(a0.y, b0.y, acc[0][0], 0, 0, 0);
        acc[0][1] = __builtin_amdgcn_mfma_f32_32x32x16_fp8_fp8(a0.y, b1.y, acc[0][1], 0, 0, 0);
        acc[1][0] = __builtin_amdgcn_mfma_f32_32x32x16_fp8_fp8(a1.y, b0.y, acc[1][0], 0, 0, 0);
        acc[1][1] = __builtin_amdgcn_mfma_f32_32x32x16_fp8_fp8(a1.y, b1.y, acc[1][1], 0, 0, 0);
    }

    // ---- certify / fallback epilogue ----
    const int*   segb  = seg + n * L;
    const float* sqb   = sq64 + n * L;
    const float* nb    = n64 + n * L;

    #pragma unroll
    for (int nf = 0; nf < 2; ++nf) {
        int k = tk * 128 + wc * 64 + nf * 32 + l31;
        float sqk = sqb[k];
        float nk  = nb[k];
        int   sgk = segb[k];
        #pragma unroll
        for (int m = 0; m < 2; ++m)
            #pragma unroll
            for (int x = 0; x < 16; ++x) {
                int j = tj * 128 + wr * 64 + m * 32 + (x & 3) + 8 * (x >> 2) + 4 * hsel;
                if (j >= k) continue;              // j<k only (weight 2); diag 0
                if (segb[j] == sgk) continue;      // same-seg: closed form
                float d2e = sqb[j] + sqk - 2.0f * acc[m][nf][x];
                float thr = 4.5f + 0.27f * nb[j] * nk;
                if (d2e >= thr) continue;          // certified hinge == 0
                // exact fp32 fallback (expected count: 0)
                const float* pj = pred + (size_t)(n * L + j) * DDIM;
                const float* pk2 = pred + (size_t)(n * L + k) * DDIM;
                float d2x = 0.0f;
                for (int d = 0; d < DDIM; ++d) {
                    float df = pj[d] - pk2[d];
                    d2x = fmaf(df, df, d2x);
                }
                if (d2x < 4.0f) {
                    float dist = sqrtf(d2x);
                    float hg = 2.0f - dist;
                    double v = (double)hg * (double)hg * 2.0 * 1073741824.0; // w=2, 2^30
                    atomicAdd(hacc, (unsigned long long)(long long)(v + 0.5));
                }
            }
    }
}

// ---------------------------------------------------------------------------
// K4: assemble loss = [ALPHA * sum_g (2 c_g T_g - 2 ||S_g||^2)
//                      + BETA * hinge_fixedpoint / 2^30] / (8 L^2).
// Single block; deterministic fixed-order reductions; int LDS histogram.
// ---------------------------------------------------------------------------
__global__ __launch_bounds__(256) void final_kernel(const float* __restrict__ Spart,
                                                    const float* __restrict__ Tpart,
                                                    const int*   __restrict__ seg,
                                                    const unsigned long long* __restrict__ hacc,
                                                    float* __restrict__ out) {
    __shared__ int cl[8][16];
    __shared__ double red[256];
    int t = threadIdx.x;
    if (t < 128) ((int*)cl)[t] = 0;
    __syncthreads();
    for (int i = t; i < NBATCH * L; i += 256) {
        int n = i >> 11;
        atomicAdd(&cl[n][seg[i]], 1);      // exact integer, deterministic
    }
    __syncthreads();

    double acc = 0.0;
    // -2 ||S||^2 over (n, g, global dim)
    for (int i = t; i < 8 * 16 * 512; i += 256) {
        int dg = i & 511, g = (i >> 9) & 15, n = i >> 13;
        int c = dg >> 5, dd = dg & 31;
        int bid0 = c * 8 + n;              // half 0
        int bid1 = bid0 + 128;             // half 1
        float s = Spart[((size_t)bid0 * 16 + g) * 32 + dd]
                + Spart[((size_t)bid1 * 16 + g) * 32 + dd];
        acc -= 2.0 * (double)s * (double)s;
    }
    // +2 c_g T_g over (n, g)
    if (t < 128) {
        int n = t >> 4, g = t & 15;
        double T = 0.0;
        #pragma unroll
        for (int c = 0; c < 16; ++c) {
            T += (double)Tpart[(c * 8 + n) * 16 + g];
            T += (double)Tpart[(c * 8 + n + 128) * 16 + g];
        }
        acc += 2.0 * (double)cl[n][g] * T;
    }
    red[t] = acc;
    __syncthreads();
    #pragma unroll
    for (int s2 = 128; s2 > 0; s2 >>= 1) {
        if (t < s2) red[t] += red[t + s2];
        __syncthreads();
    }
    if (t == 0) {
        double same  = red[0];
        double hinge = (double)(long long)hacc[0] / 1073741824.0;
        double loss  = (ALPHA * same + BETA * hinge)
                     / ((double)NBATCH * (double)L * (double)L);
        out[0] = (float)loss;
    }
}

extern "C" void kernel_launch(void* const* d_in, const int* in_sizes, int n_in,
                              void* d_out, int out_size, void* d_ws, size_t ws_size,
                              hipStream_t stream) {
    const float* pred = (const float*)d_in[0];
    const int*   seg  = (const int*)d_in[1];
    float* out = (float*)d_out;

    // workspace layout
    unsigned char* h8   = (unsigned char*)d_ws;                 // 1 MB packed fp8 (64 dims)
    float* sq64         = (float*)(h8 + 512 * PAN2);            // 64 KB
    float* n64          = sq64 + NBATCH * L;                    // 64 KB
    float* Spart        = n64 + NBATCH * L;                     // 512 KB
    float* Tpart        = Spart + 256 * 16 * 32;                // 16 KB
    unsigned long long* hacc = (unsigned long long*)(Tpart + 256 * 16);

    hipMemsetAsync(hacc, 0, sizeof(unsigned long long), stream);
    gsum_kernel<<<256, 256, 0, stream>>>(pred, seg, Spart, Tpart);
    conv64_kernel<<<512, 256, 0, stream>>>(pred, h8, sq64, n64);
    screen_kernel<<<SCREEN_BLOCKS, 256, 0, stream>>>(h8, sq64, n64, seg, pred, hacc);
    final_kernel<<<1, 256, 0, stream>>>(Spart, Tpart, seg, hacc, out);
}

// Round 23
// 57.538 us; speedup vs baseline: 2.5113x; 2.5113x over previous
//
#include <hip/hip_runtime.h>
#include <hip/hip_fp8.h>
#include <math.h>

#define L      2048
#define DDIM   512
#define NBATCH 8
#define NTILE  16                        // 128-row tiles
#define NPAIR  (NTILE * (NTILE + 1) / 2) // 136
#define SCREEN_BLOCKS (NBATCH * NPAIR)   // 1088

#define ALPHA  0.1
#define BETA   0.3
#define PAN2   2048      // bytes per packed 32-row x 64-dim fp8 panel

typedef __attribute__((ext_vector_type(16))) float f32x16;
typedef long long2v __attribute__((ext_vector_type(2)));

// ---------------------------------------------------------------------------
// K1: per-(batch, 32-dim chunk, quarter) group sums + integer counts.
// grid 512 = 8 n x 16 chunks x 4 quarters; 256 thr = 8 row-parts x 32 dims.
// Blocks with c==0 also histogram seg (integer atomics -> deterministic).
// ---------------------------------------------------------------------------
__global__ __launch_bounds__(256) void gsum_kernel(const float* __restrict__ pred,
                                                   const int*   __restrict__ seg,
                                                   float* __restrict__ Spart,
                                                   float* __restrict__ Tpart,
                                                   int*   __restrict__ counts) {
    __shared__ float Sl[8][16][32];
    __shared__ float Tl[8][16][32];
    __shared__ int   ch[16];
    int bid = blockIdx.x;
    int n   = bid & 7;
    int c   = (bid >> 3) & 15;
    int qtr = bid >> 7;                  // 0..3
    int t = threadIdx.x;
    int d = t & 31, p = t >> 5;

    for (int i = t; i < 8 * 16 * 32; i += 256) {
        ((float*)Sl)[i] = 0.0f;
        ((float*)Tl)[i] = 0.0f;
    }
    if (t < 16) ch[t] = 0;
    __syncthreads();

    const float* pb   = pred + (size_t)n * L * DDIM + c * 32 + d;
    const int*   segb = seg + n * L + qtr * 512;
    #pragma unroll 4
    for (int i = 0; i < 64; ++i) {
        int lr  = i * 8 + p;                       // 0..511 within quarter
        int row = qtr * 512 + lr;
        float x = pb[(size_t)row * DDIM];
        int g   = segb[lr];
        Sl[p][g][d] += x;
        Tl[p][g][d] += x * x;
    }
    __syncthreads();

    for (int i = t; i < 512; i += 256) {
        int g = i >> 5, dd = i & 31;
        float s = 0.0f, tt = 0.0f;
        #pragma unroll
        for (int q = 0; q < 8; ++q) { s += Sl[q][g][dd]; tt += Tl[q][g][dd]; }
        Spart[((size_t)bid * 16 + g) * 32 + dd] = s;
        Sl[0][g][dd] = tt;
    }
    __syncthreads();
    if (t < 16) {
        float tt = 0.0f;
        #pragma unroll
        for (int dd = 0; dd < 32; ++dd) tt += Sl[0][t][dd];
        Tpart[bid * 16 + t] = tt;
    }
    if (c == 0) {
        for (int i = t; i < 512; i += 256) atomicAdd(&ch[segb[i]], 1);
        __syncthreads();
        if (t < 16) atomicAdd(&counts[n * 16 + t], ch[t]);
    }
}

// ---------------------------------------------------------------------------
// K2: first-64-dims fp32 -> fp8 e4m3 packed in MFMA-fragment order
// (R20/R21-verified layout) + exact fp32 sq64 / n64.
// ---------------------------------------------------------------------------
__global__ __launch_bounds__(256) void conv64_kernel(const float* __restrict__ pred,
                                                     unsigned char* __restrict__ h8,
                                                     float* __restrict__ sq64,
                                                     float* __restrict__ n64) {
    int t    = threadIdx.x;
    int rowl = t >> 3;
    int d8   = t & 7;
    int row  = blockIdx.x * 32 + rowl;
    const float* p = pred + (size_t)row * DDIM + d8 * 8;
    float4 v0 = *(const float4*)(p);
    float4 v1 = *(const float4*)(p + 4);
    float vals[8] = {v0.x, v0.y, v0.z, v0.w, v1.x, v1.y, v1.z, v1.w};
    unsigned q[8];
    float s = 0.0f;
    #pragma unroll
    for (int i = 0; i < 8; ++i) {
        float x = vals[i];
        s = fmaf(x, x, s);
        __hip_fp8_e4m3 f8(x);
        q[i] = (unsigned)f8.__x;
    }
    unsigned lo = q[0] | (q[1] << 8) | (q[2] << 16) | (q[3] << 24);
    unsigned hi = q[4] | (q[5] << 8) | (q[6] << 16) | (q[7] << 24);
    int pair  = d8 >> 2;
    int kodd  = (d8 >> 1) & 1;
    int khalf = d8 & 1;
    size_t off = (size_t)blockIdx.x * PAN2 + pair * 1024
               + ((row & 31) + 32 * khalf) * 16 + kodd * 8;
    *(uint2*)(h8 + off) = make_uint2(lo, hi);
    s += __shfl_down(s, 4);
    s += __shfl_down(s, 2);
    s += __shfl_down(s, 1);
    if (d8 == 0) { sq64[row] = s; n64[row] = sqrtf(s); }
}

// ---------------------------------------------------------------------------
// K3: 64-dim fp8 screen GEMM (register-direct). Certifies hinge==0 when
// d2_est >= 4.5 + 0.27*nj*nk (rigorous e4m3 bound; d2_512 >= d2_64).
// Survivors -> exact fp32 fallback, int64 fixed-point atomic (deterministic).
// ---------------------------------------------------------------------------
__global__ __launch_bounds__(256) void screen_kernel(
        const unsigned char* __restrict__ h8,
        const float* __restrict__ sq64,
        const float* __restrict__ n64,
        const int*   __restrict__ seg,
        const float* __restrict__ pred,
        unsigned long long* __restrict__ hacc) {
    int bid = blockIdx.x;
    int n = bid & 7;
    int p = bid >> 3;
    int tj = 0;
    while (true) {
        int rl2 = NTILE - tj;
        if (p < rl2) break;
        p -= rl2;
        ++tj;
    }
    int tk = tj + p;

    int t    = threadIdx.x;
    int wid  = t >> 6;
    int lane = t & 63;
    int wr   = wid >> 1, wc = wid & 1;
    int l31  = lane & 31;
    int hsel = lane >> 5;

    const unsigned char* pa0 = h8 + (size_t)(n * 64 + tj * 4 + wr * 2 + 0) * PAN2 + lane * 16;
    const unsigned char* pa1 = pa0 + PAN2;
    const unsigned char* pb0 = h8 + (size_t)(n * 64 + tk * 4 + wc * 2 + 0) * PAN2 + lane * 16;
    const unsigned char* pb1 = pb0 + PAN2;

    f32x16 acc[2][2];
    #pragma unroll
    for (int m = 0; m < 2; ++m)
        #pragma unroll
        for (int nf = 0; nf < 2; ++nf)
            #pragma unroll
            for (int x = 0; x < 16; ++x) acc[m][nf][x] = 0.0f;

    #pragma unroll
    for (int ks2 = 0; ks2 < 2; ++ks2) {
        long2v a0 = *(const long2v*)(pa0 + ks2 * 1024);
        long2v a1 = *(const long2v*)(pa1 + ks2 * 1024);
        long2v b0 = *(const long2v*)(pb0 + ks2 * 1024);
        long2v b1 = *(const long2v*)(pb1 + ks2 * 1024);
        acc[0][0] = __builtin_amdgcn_mfma_f32_32x32x16_fp8_fp8(a0.x, b0.x, acc[0][0], 0, 0, 0);
        acc[0][1] = __builtin_amdgcn_mfma_f32_32x32x16_fp8_fp8(a0.x, b1.x, acc[0][1], 0, 0, 0);
        acc[1][0] = __builtin_amdgcn_mfma_f32_32x32x16_fp8_fp8(a1.x, b0.x, acc[1][0], 0, 0, 0);
        acc[1][1] = __builtin_amdgcn_mfma_f32_32x32x16_fp8_fp8(a1.x, b1.x, acc[1][1], 0, 0, 0);
        acc[0][0] = __builtin_amdgcn_mfma_f32_32x32x16_fp8_fp8(a0.y, b0.y, acc[0][0], 0, 0, 0);
        acc[0][1] = __builtin_amdgcn_mfma_f32_32x32x16_fp8_fp8(a0.y, b1.y, acc[0][1], 0, 0, 0);
        acc[1][0] = __builtin_amdgcn_mfma_f32_32x32x16_fp8_fp8(a1.y, b0.y, acc[1][0], 0, 0, 0);
        acc[1][1] = __builtin_amdgcn_mfma_f32_32x32x16_fp8_fp8(a1.y, b1.y, acc[1][1], 0, 0, 0);
    }

    const int*   segb = seg + n * L;
    const float* sqb  = sq64 + n * L;
    const float* nb   = n64 + n * L;

    #pragma unroll
    for (int nf = 0; nf < 2; ++nf) {
        int k = tk * 128 + wc * 64 + nf * 32 + l31;
        float sqk = sqb[k];
        float nk  = nb[k];
        int   sgk = segb[k];
        #pragma unroll
        for (int m = 0; m < 2; ++m)
            #pragma unroll
            for (int x = 0; x < 16; ++x) {
                int j = tj * 128 + wr * 64 + m * 32 + (x & 3) + 8 * (x >> 2) + 4 * hsel;
                if (j >= k) continue;
                if (segb[j] == sgk) continue;
                float d2e = sqb[j] + sqk - 2.0f * acc[m][nf][x];
                float thr = 4.5f + 0.27f * nb[j] * nk;
                if (d2e >= thr) continue;
                const float* pj  = pred + (size_t)(n * L + j) * DDIM;
                const float* pk2 = pred + (size_t)(n * L + k) * DDIM;
                float d2x = 0.0f;
                for (int d = 0; d < DDIM; ++d) {
                    float df = pj[d] - pk2[d];
                    d2x = fmaf(df, df, d2x);
                }
                if (d2x < 4.0f) {
                    float dist = sqrtf(d2x);
                    float hg = 2.0f - dist;
                    double v = (double)hg * (double)hg * 2.0 * 1073741824.0;
                    atomicAdd(hacc, (unsigned long long)(long long)(v + 0.5));
                }
            }
    }
}

// ---------------------------------------------------------------------------
// K4: per-(n,g) closed-form value: gval = 2*c_g*T_g - 2*||S_g||^2.
// 128 blocks (one per (n,g)), 256 threads.
// ---------------------------------------------------------------------------
__global__ __launch_bounds__(256) void pergroup_kernel(const float* __restrict__ Spart,
                                                       const float* __restrict__ Tpart,
                                                       const int*   __restrict__ counts,
                                                       double* __restrict__ gval) {
    __shared__ double red[256];
    int bid = blockIdx.x;
    int n = bid >> 4, g = bid & 15;
    int t = threadIdx.x;
    int cnt = counts[n * 16 + g];

    double a = 0.0;
    for (int dg = t; dg < 512; dg += 256) {
        int c = dg >> 5, dd = dg & 31;
        float s = 0.0f;
        #pragma unroll
        for (int q = 0; q < 4; ++q)
            s += Spart[((size_t)(q * 128 + c * 8 + n) * 16 + g) * 32 + dd];
        a -= 2.0 * (double)s * (double)s;
    }
    if (t < 64) {
        int q = t >> 4, c = t & 15;
        a += 2.0 * (double)cnt * (double)Tpart[(q * 128 + c * 8 + n) * 16 + g];
    }
    red[t] = a;
    __syncthreads();
    #pragma unroll
    for (int s2 = 128; s2 > 0; s2 >>= 1) {
        if (t < s2) red[t] += red[t + s2];
        __syncthreads();
    }
    if (t == 0) gval[bid] = red[0];
}

// ---------------------------------------------------------------------------
// K5: final assembly (tiny).
// ---------------------------------------------------------------------------
__global__ __launch_bounds__(128) void final_kernel(const double* __restrict__ gval,
                                                    const unsigned long long* __restrict__ hacc,
                                                    float* __restrict__ out) {
    __shared__ double red[128];
    int t = threadIdx.x;
    red[t] = gval[t];
    __syncthreads();
    #pragma unroll
    for (int s2 = 64; s2 > 0; s2 >>= 1) {
        if (t < s2) red[t] += red[t + s2];
        __syncthreads();
    }
    if (t == 0) {
        double hinge = (double)(long long)hacc[0] / 1073741824.0;
        double loss  = (ALPHA * red[0] + BETA * hinge)
                     / ((double)NBATCH * (double)L * (double)L);
        out[0] = (float)loss;
    }
}

extern "C" void kernel_launch(void* const* d_in, const int* in_sizes, int n_in,
                              void* d_out, int out_size, void* d_ws, size_t ws_size,
                              hipStream_t stream) {
    const float* pred = (const float*)d_in[0];
    const int*   seg  = (const int*)d_in[1];
    float* out = (float*)d_out;

    unsigned char* h8   = (unsigned char*)d_ws;                 // 1 MB packed fp8
    float* sq64         = (float*)(h8 + 512 * PAN2);            // 64 KB
    float* n64          = sq64 + NBATCH * L;                    // 64 KB
    float* Spart        = n64 + NBATCH * L;                     // 1 MB (512*16*32)
    float* Tpart        = Spart + 512 * 16 * 32;                // 32 KB
    unsigned long long* hacc = (unsigned long long*)(Tpart + 512 * 16);
    int*   counts       = (int*)(hacc + 1);                     // 512 B
    double* gval        = (double*)(counts + 128);              // 1 KB

    hipMemsetAsync(hacc, 0, 8 + 512, stream);                   // hacc + counts
    gsum_kernel<<<512, 256, 0, stream>>>(pred, seg, Spart, Tpart, counts);
    conv64_kernel<<<512, 256, 0, stream>>>(pred, h8, sq64, n64);
    screen_kernel<<<SCREEN_BLOCKS, 256, 0, stream>>>(h8, sq64, n64, seg, pred, hacc);
    pergroup_kernel<<<128, 256, 0, stream>>>(Spart, Tpart, counts, gval);
    final_kernel<<<1, 128, 0, stream>>>(gval, hacc, out);
}

// Round 24
// 55.921 us; speedup vs baseline: 2.5839x; 1.0289x over previous
//
#include <hip/hip_runtime.h>
#include <hip/hip_fp8.h>
#include <math.h>

#define L      2048
#define DDIM   512
#define NBATCH 8
#define NTILE  16                        // 128-row tiles
#define NPAIR  (NTILE * (NTILE + 1) / 2) // 136
#define SCREEN_BLOCKS (NBATCH * NPAIR)   // 1088

#define ALPHA  0.1
#define BETA   0.3
#define PAN2   2048      // bytes per packed 32-row x 64-dim fp8 panel

typedef __attribute__((ext_vector_type(16))) float f32x16;
typedef long long2v __attribute__((ext_vector_type(2)));

// ---------------------------------------------------------------------------
// K1: per-(batch, 32-dim chunk, quarter) group sums (S per-dim, T scalar).
// grid 512 = 8 n x 16 chunks x 4 quarters; 256 thr = 8 row-parts x 32 dims.
// No atomics, no pre-zeroed globals.
// ---------------------------------------------------------------------------
__global__ __launch_bounds__(256) void gsum_kernel(const float* __restrict__ pred,
                                                   const int*   __restrict__ seg,
                                                   float* __restrict__ Spart,
                                                   float* __restrict__ Tpart) {
    __shared__ float Sl[8][16][32];
    __shared__ float Tl[8][16][32];
    int bid = blockIdx.x;
    int n   = bid & 7;
    int c   = (bid >> 3) & 15;
    int qtr = bid >> 7;                  // 0..3
    int t = threadIdx.x;
    int d = t & 31, p = t >> 5;

    for (int i = t; i < 8 * 16 * 32; i += 256) {
        ((float*)Sl)[i] = 0.0f;
        ((float*)Tl)[i] = 0.0f;
    }
    __syncthreads();

    const float* pb   = pred + (size_t)n * L * DDIM + c * 32 + d;
    const int*   segb = seg + n * L + qtr * 512;
    #pragma unroll 4
    for (int i = 0; i < 64; ++i) {
        int lr  = i * 8 + p;                       // 0..511 within quarter
        int row = qtr * 512 + lr;
        float x = pb[(size_t)row * DDIM];
        int g   = segb[lr];
        Sl[p][g][d] += x;
        Tl[p][g][d] += x * x;
    }
    __syncthreads();

    for (int i = t; i < 512; i += 256) {
        int g = i >> 5, dd = i & 31;
        float s = 0.0f, tt = 0.0f;
        #pragma unroll
        for (int q = 0; q < 8; ++q) { s += Sl[q][g][dd]; tt += Tl[q][g][dd]; }
        Spart[((size_t)bid * 16 + g) * 32 + dd] = s;
        Sl[0][g][dd] = tt;
    }
    __syncthreads();
    if (t < 16) {
        float tt = 0.0f;
        #pragma unroll
        for (int dd = 0; dd < 32; ++dd) tt += Sl[0][t][dd];
        Tpart[bid * 16 + t] = tt;
    }
}

// ---------------------------------------------------------------------------
// K2: first-64-dims fp32 -> fp8 e4m3 packed in MFMA-fragment order
// (R20/R21-verified layout) + exact fp32 sq64 / n64.
// ---------------------------------------------------------------------------
__global__ __launch_bounds__(256) void conv64_kernel(const float* __restrict__ pred,
                                                     unsigned char* __restrict__ h8,
                                                     float* __restrict__ sq64,
                                                     float* __restrict__ n64) {
    int t    = threadIdx.x;
    int rowl = t >> 3;
    int d8   = t & 7;
    int row  = blockIdx.x * 32 + rowl;
    const float* p = pred + (size_t)row * DDIM + d8 * 8;
    float4 v0 = *(const float4*)(p);
    float4 v1 = *(const float4*)(p + 4);
    float vals[8] = {v0.x, v0.y, v0.z, v0.w, v1.x, v1.y, v1.z, v1.w};
    unsigned q[8];
    float s = 0.0f;
    #pragma unroll
    for (int i = 0; i < 8; ++i) {
        float x = vals[i];
        s = fmaf(x, x, s);
        __hip_fp8_e4m3 f8(x);
        q[i] = (unsigned)f8.__x;
    }
    unsigned lo = q[0] | (q[1] << 8) | (q[2] << 16) | (q[3] << 24);
    unsigned hi = q[4] | (q[5] << 8) | (q[6] << 16) | (q[7] << 24);
    int pair  = d8 >> 2;
    int kodd  = (d8 >> 1) & 1;
    int khalf = d8 & 1;
    size_t off = (size_t)blockIdx.x * PAN2 + pair * 1024
               + ((row & 31) + 32 * khalf) * 16 + kodd * 8;
    *(uint2*)(h8 + off) = make_uint2(lo, hi);
    s += __shfl_down(s, 4);
    s += __shfl_down(s, 2);
    s += __shfl_down(s, 1);
    if (d8 == 0) { sq64[row] = s; n64[row] = sqrtf(s); }
}

// ---------------------------------------------------------------------------
// K3: 64-dim fp8 screen GEMM (register-direct). Certifies hinge==0 when
// d2_est >= 4.5 + 0.27*nj*nk (rigorous e4m3 bound; d2_512 >= d2_64).
// Survivors -> exact fp32 fallback. Per-block hinge partial written
// UNCONDITIONALLY to hpart[bid] (no atomics, no pre-zeroing, deterministic).
// ---------------------------------------------------------------------------
__global__ __launch_bounds__(256) void screen_kernel(
        const unsigned char* __restrict__ h8,
        const float* __restrict__ sq64,
        const float* __restrict__ n64,
        const int*   __restrict__ seg,
        const float* __restrict__ pred,
        double* __restrict__ hpart) {
    __shared__ double wred[4];
    int bid = blockIdx.x;
    int n = bid & 7;
    int p = bid >> 3;
    int tj = 0;
    while (true) {
        int rl2 = NTILE - tj;
        if (p < rl2) break;
        p -= rl2;
        ++tj;
    }
    int tk = tj + p;

    int t    = threadIdx.x;
    int wid  = t >> 6;
    int lane = t & 63;
    int wr   = wid >> 1, wc = wid & 1;
    int l31  = lane & 31;
    int hsel = lane >> 5;

    const unsigned char* pa0 = h8 + (size_t)(n * 64 + tj * 4 + wr * 2 + 0) * PAN2 + lane * 16;
    const unsigned char* pa1 = pa0 + PAN2;
    const unsigned char* pb0 = h8 + (size_t)(n * 64 + tk * 4 + wc * 2 + 0) * PAN2 + lane * 16;
    const unsigned char* pb1 = pb0 + PAN2;

    f32x16 acc[2][2];
    #pragma unroll
    for (int m = 0; m < 2; ++m)
        #pragma unroll
        for (int nf = 0; nf < 2; ++nf)
            #pragma unroll
            for (int x = 0; x < 16; ++x) acc[m][nf][x] = 0.0f;

    #pragma unroll
    for (int ks2 = 0; ks2 < 2; ++ks2) {
        long2v a0 = *(const long2v*)(pa0 + ks2 * 1024);
        long2v a1 = *(const long2v*)(pa1 + ks2 * 1024);
        long2v b0 = *(const long2v*)(pb0 + ks2 * 1024);
        long2v b1 = *(const long2v*)(pb1 + ks2 * 1024);
        acc[0][0] = __builtin_amdgcn_mfma_f32_32x32x16_fp8_fp8(a0.x, b0.x, acc[0][0], 0, 0, 0);
        acc[0][1] = __builtin_amdgcn_mfma_f32_32x32x16_fp8_fp8(a0.x, b1.x, acc[0][1], 0, 0, 0);
        acc[1][0] = __builtin_amdgcn_mfma_f32_32x32x16_fp8_fp8(a1.x, b0.x, acc[1][0], 0, 0, 0);
        acc[1][1] = __builtin_amdgcn_mfma_f32_32x32x16_fp8_fp8(a1.x, b1.x, acc[1][1], 0, 0, 0);
        acc[0][0] = __builtin_amdgcn_mfma_f32_32x32x16_fp8_fp8(a0.y, b0.y, acc[0][0], 0, 0, 0);
        acc[0][1] = __builtin_amdgcn_mfma_f32_32x32x16_fp8_fp8(a0.y, b1.y, acc[0][1], 0, 0, 0);
        acc[1][0] = __builtin_amdgcn_mfma_f32_32x32x16_fp8_fp8(a1.y, b0.y, acc[1][0], 0, 0, 0);
        acc[1][1] = __builtin_amdgcn_mfma_f32_32x32x16_fp8_fp8(a1.y, b1.y, acc[1][1], 0, 0, 0);
    }

    const int*   segb = seg + n * L;
    const float* sqb  = sq64 + n * L;
    const float* nb   = n64 + n * L;

    double hsum = 0.0;
    #pragma unroll
    for (int nf = 0; nf < 2; ++nf) {
        int k = tk * 128 + wc * 64 + nf * 32 + l31;
        float sqk = sqb[k];
        float nk  = nb[k];
        int   sgk = segb[k];
        #pragma unroll
        for (int m = 0; m < 2; ++m)
            #pragma unroll
            for (int x = 0; x < 16; ++x) {
                int j = tj * 128 + wr * 64 + m * 32 + (x & 3) + 8 * (x >> 2) + 4 * hsel;
                if (j >= k) continue;
                if (segb[j] == sgk) continue;
                float d2e = sqb[j] + sqk - 2.0f * acc[m][nf][x];
                float thr = 4.5f + 0.27f * nb[j] * nk;
                if (d2e >= thr) continue;          // certified hinge == 0
                const float* pj  = pred + (size_t)(n * L + j) * DDIM;
                const float* pk2 = pred + (size_t)(n * L + k) * DDIM;
                float d2x = 0.0f;
                for (int d = 0; d < DDIM; ++d) {
                    float df = pj[d] - pk2[d];
                    d2x = fmaf(df, df, d2x);
                }
                if (d2x < 4.0f) {
                    float dist = sqrtf(d2x);
                    float hg = 2.0f - dist;
                    hsum += (double)hg * (double)hg * 2.0;   // weight 2 (j<k)
                }
            }
    }

    // deterministic in-block reduction; unconditional slot write
    #pragma unroll
    for (int off = 32; off > 0; off >>= 1)
        hsum += __shfl_down(hsum, off);
    if (lane == 0) wred[wid] = hsum;
    __syncthreads();
    if (t == 0) hpart[bid] = (wred[0] + wred[1]) + (wred[2] + wred[3]);
}

// ---------------------------------------------------------------------------
// K4: per-(n,g) closed-form value: gval = 2*c_g*T_g - 2*||S_g||^2.
// 128 blocks; counts computed locally from seg (no atomics).
// ---------------------------------------------------------------------------
__global__ __launch_bounds__(256) void pergroup_kernel(const float* __restrict__ Spart,
                                                       const float* __restrict__ Tpart,
                                                       const int*   __restrict__ seg,
                                                       double* __restrict__ gval) {
    __shared__ double red[256];
    __shared__ int cl[64];
    int bid = blockIdx.x;
    int n = bid >> 4, g = bid & 15;
    int t = threadIdx.x;

    // count rows with seg == g in batch n (deterministic integer sum)
    const int* segb = seg + n * L;
    int cnt = 0;
    for (int i = t; i < L; i += 256) cnt += (segb[i] == g);
    #pragma unroll
    for (int off = 32; off > 0; off >>= 1) cnt += __shfl_down(cnt, off);
    if ((t & 63) == 0) cl[t >> 6] = cnt;
    __syncthreads();
    int c_g = cl[0] + cl[1] + cl[2] + cl[3];

    double a = 0.0;
    for (int dg = t; dg < 512; dg += 256) {
        int c = dg >> 5, dd = dg & 31;
        float s = 0.0f;
        #pragma unroll
        for (int q = 0; q < 4; ++q)
            s += Spart[((size_t)(q * 128 + c * 8 + n) * 16 + g) * 32 + dd];
        a -= 2.0 * (double)s * (double)s;
    }
    if (t < 64) {
        int q = t >> 4, c = t & 15;
        a += 2.0 * (double)c_g * (double)Tpart[(q * 128 + c * 8 + n) * 16 + g];
    }
    red[t] = a;
    __syncthreads();
    #pragma unroll
    for (int s2 = 128; s2 > 0; s2 >>= 1) {
        if (t < s2) red[t] += red[t + s2];
        __syncthreads();
    }
    if (t == 0) gval[bid] = red[0];
}

// ---------------------------------------------------------------------------
// K5: final assembly: sum 128 gval + 1088 hpart -> loss.
// ---------------------------------------------------------------------------
__global__ __launch_bounds__(256) void final_kernel(const double* __restrict__ gval,
                                                    const double* __restrict__ hpart,
                                                    float* __restrict__ out) {
    __shared__ double red[256];
    int t = threadIdx.x;
    double a = 0.0;
    if (t < 128) a = ALPHA * gval[t];
    for (int i = t; i < SCREEN_BLOCKS; i += 256) a += BETA * hpart[i];
    red[t] = a;
    __syncthreads();
    #pragma unroll
    for (int s2 = 128; s2 > 0; s2 >>= 1) {
        if (t < s2) red[t] += red[t + s2];
        __syncthreads();
    }
    if (t == 0)
        out[0] = (float)(red[0] / ((double)NBATCH * (double)L * (double)L));
}

extern "C" void kernel_launch(void* const* d_in, const int* in_sizes, int n_in,
                              void* d_out, int out_size, void* d_ws, size_t ws_size,
                              hipStream_t stream) {
    const float* pred = (const float*)d_in[0];
    const int*   seg  = (const int*)d_in[1];
    float* out = (float*)d_out;

    unsigned char* h8   = (unsigned char*)d_ws;                 // 1 MB packed fp8
    float* sq64         = (float*)(h8 + 512 * PAN2);            // 64 KB
    float* n64          = sq64 + NBATCH * L;                    // 64 KB
    float* Spart        = n64 + NBATCH * L;                     // 1 MB (512*16*32)
    float* Tpart        = Spart + 512 * 16 * 32;                // 32 KB
    double* hpart       = (double*)(Tpart + 512 * 16);          // 8.7 KB
    double* gval        = hpart + SCREEN_BLOCKS;                // 1 KB

    gsum_kernel<<<512, 256, 0, stream>>>(pred, seg, Spart, Tpart);
    conv64_kernel<<<512, 256, 0, stream>>>(pred, h8, sq64, n64);
    screen_kernel<<<SCREEN_BLOCKS, 256, 0, stream>>>(h8, sq64, n64, seg, pred, hpart);
    pergroup_kernel<<<128, 256, 0, stream>>>(Spart, Tpart, seg, gval);
    final_kernel<<<1, 256, 0, stream>>>(gval, hpart, out);
}